// Round 13
// baseline (119.214 us; speedup 1.0000x reference)
//
#include <hip/hip_runtime.h>
#include <math.h>

#define N_LAYERS 200
#define KSIZE 7
#define L_IN 1388
#define FC_IN 188
#define FC_OUT 91
#define NT 128        // 2 waves per row, independent between repacks
#define RMAX 12
#define NSTAGES 13    // 12 stages of 16 layers (margin 96) + 1 of 8 (margin 48)

// ---- Stage tables (2-wave split, margin = 6 * stage_layers) ----
constexpr int s_lo(int s)  { return 16 * s; }
constexpr int s_hi(int s)  { return (s < 12) ? 16 * s + 16 : N_LAYERS; }
constexpr int lin_(int s)  { return L_IN - 6 * s_lo(s); }
constexpr int lout_(int s) { return L_IN - 6 * s_hi(s); }
constexpr int cut_(int s)  { return lout_(s) / 2; }
constexpr int marg_(int s) { return 6 * (s_hi(s) - s_lo(s)); }
constexpr int s_R(int s) {
    const int a = cut_(s) + marg_(s);
    const int b = lin_(s) - cut_(s);
    const int m = (a > b) ? a : b;
    return (m + 63) / 64;                    // 12,11,11,10,9,8,8,7,6,5,5,4,3
}

// lane i <- lane i+1 (wave_shl:1 = ctrl 0x130). Lane 63 gets 0 via
// bound_ctrl -> lands in the garbage-creep margin.
__device__ __forceinline__ float dpp_next(float v) {
    return __int_as_float(
        __builtin_amdgcn_mov_dpp(__float_as_int(v), 0x130, 0xf, 0xf, true));
}

// 4-layer weight group: 28 taps + 4 biases via 8 s_load_x4 (SGPR-resident).
struct WG { float w[28]; float b[4]; };

__device__ __forceinline__ void load_wg(WG& wg, const float4* __restrict__ cw4,
                                        const float4* __restrict__ cb4, int g) {
#pragma unroll
    for (int t = 0; t < 7; ++t) {
        const float4 v = cw4[g * 7 + t];
        wg.w[4 * t + 0] = v.x; wg.w[4 * t + 1] = v.y;
        wg.w[4 * t + 2] = v.z; wg.w[4 * t + 3] = v.w;
    }
    const float4 bv = cb4[g];
    wg.b[0] = bv.x; wg.b[1] = bv.y; wg.b[2] = bv.z; wg.b[3] = bv.w;
}

// 4 layers with R values/lane, D-MAJOR accumulation with SCHED FENCES:
// sched_barrier(0) after every tap row pins the interleaved schedule --
// R independent FMAs issue back-to-back (dep distance R >> FMA latency),
// so a wave sustains ~1 VALU / 2 cyc instead of serializing each output's
// 7-deep chain (rounds 9-12: VGPR=16-20 proved the backend re-serialized;
// VALU idle ~75%). Halo/in-place/margin invariants as rounds 9-12.
template<int R, bool NR3>
__device__ __forceinline__ void run4(float (&r)[RMAX], const WG& wg) {
    constexpr int T1N = (R < 6) ? R : 6;
    constexpr int T2N = (R < 6) ? (6 - R) : 0;
#pragma unroll
    for (int j = 0; j < 4; ++j) {
        float t1[T1N];
#pragma unroll
        for (int t = 0; t < T1N; ++t) t1[t] = dpp_next(r[t]);
        float t2[T2N ? T2N : 1];
        if constexpr (T2N > 0) {
#pragma unroll
            for (int u = 0; u < T2N; ++u) t2[u] = dpp_next(t1[u]);
        }
        __builtin_amdgcn_sched_barrier(0);

        float acc[R];
#pragma unroll
        for (int d = 0; d < KSIZE; ++d) {
            const float wd = wg.w[j * 7 + d];
#pragma unroll
            for (int k = 0; k < R; ++k) {
                const int m = k + d;  // compile-time select of source
                const float v = (m < R) ? r[m]
                              : ((m - R < T1N) ? t1[m - R] : t2[m - 2 * R]);
                acc[k] = (d == 0) ? fmaf(wd, v, wg.b[j]) : fmaf(wd, v, acc[k]);
            }
            __builtin_amdgcn_sched_barrier(0);  // fence: next tap row stays after
        }

        const bool relu = !(NR3 && j == 3);
#pragma unroll
        for (int k = 0; k < R; ++k)
            r[k] = relu ? fmaxf(acc[k], 0.0f) : acc[k];
        __builtin_amdgcn_sched_barrier(0);
    }
}

// Stage = groups [g0,g1), ping-pong weight double-buffer: while a group
// computes, the next group's 8 s_load_x4 are in flight.
template<int R, bool FINAL>
__device__ __forceinline__ void run_stage_g(float (&r)[RMAX], WG& A,
        const float4* __restrict__ cw4, const float4* __restrict__ cb4,
        int g0, int g1) {
#pragma unroll 1
    for (int g = g0; g < g1; g += 2) {
        WG B;
        load_wg(B, cw4, cb4, (g + 1 < 50) ? g + 1 : 49);
        run4<R, false>(r, A);
        load_wg(A, cw4, cb4, (g + 2 < 50) ? g + 2 : 49);
        run4<R, FINAL>(r, B);
    }
}

// Cross-wave repack after stage s: write owned valid values at global row
// positions, barrier, read next stage's region, barrier.
template<int Ro, int Rn>
__device__ __forceinline__ void repack(float (&r)[RMAX], float* lbuf,
                                       int lane, int wid,
                                       int cut_o, int lout_o, int cut_n)
{
    const int base_o = wid ? cut_o : 0;
    const int bound  = wid ? lout_o : cut_o;
#pragma unroll
    for (int k = 0; k < Ro; ++k) {
        const int g = base_o + lane * Ro + k;
        if (g < bound) lbuf[g] = r[k];
    }
    __syncthreads();
    const int base_n = wid ? cut_n : 0;
#pragma unroll
    for (int k = 0; k < Rn; ++k) r[k] = lbuf[base_n + lane * Rn + k];
    __syncthreads();
}

template<int S>
struct Chain {
    __device__ static __forceinline__ void run(float (&r)[RMAX], WG& A,
        const float4* __restrict__ cw4, const float4* __restrict__ cb4,
        float* lbuf, int lane, int wid)
    {
        run_stage_g<s_R(S), false>(r, A, cw4, cb4, 4 * S, 4 * S + 4);
        repack<s_R(S), s_R(S + 1)>(r, lbuf, lane, wid,
                                   cut_(S), lout_(S), cut_(S + 1));
        Chain<S + 1>::run(r, A, cw4, cb4, lbuf, lane, wid);
    }
};

template<>
struct Chain<NSTAGES - 1> {
    __device__ static __forceinline__ void run(float (&r)[RMAX], WG& A,
        const float4* __restrict__ cw4, const float4* __restrict__ cb4,
        float* lbuf, int lane, int wid)
    {
        constexpr int R = s_R(NSTAGES - 1);  // 3; groups 48,49 (layer 199 no ReLU)
        run_stage_g<R, true>(r, A, cw4, cb4, 48, 50);
        // final gather: wave0 owns [0,94), wave1 [94,188) -> lbuf[0..188)
        const int base_o = wid ? 94 : 0;
        const int bound  = wid ? FC_IN : 94;
#pragma unroll
        for (int k = 0; k < R; ++k) {
            const int g = base_o + lane * R + k;
            if (g < bound) lbuf[g] = r[k];
        }
        __syncthreads();
    }
};

__global__ __launch_bounds__(NT, 2) void conv_chain_kernel(
    const float* __restrict__ x,
    const float* __restrict__ conv_w,
    const float* __restrict__ conv_b,
    const float* __restrict__ fc_w,
    const float* __restrict__ fc_b,
    float* __restrict__ out)
{
    // max repack read index: cut(1) + 64*R(1) = 598 + 704 = 1302 -> 1312
    __shared__ __align__(16) float lbuf[1312];

    const int row  = blockIdx.x;
    const int tid  = threadIdx.x;
    const int lane = tid & 63;
    const int wid  = tid >> 6;

    const float4* cw4 = (const float4*)conv_w;  // 1400 floats = 350 float4
    const float4* cb4 = (const float4*)conv_b;  // 200 floats = 50 float4

    // Preload group 0's weights (rolling ping-pong starts here).
    WG A;
    load_wg(A, cw4, cb4, 0);

    // Stage-0 region load from global: wave0 base 0, wave1 base cut(0)=646.
    float r[RMAX];
    const float* xr = x + (size_t)row * L_IN;
    constexpr int R0 = s_R(0);               // 12
    const int c0 = wid ? cut_(0) : 0;
#pragma unroll
    for (int k = 0; k < R0; ++k) {
        const int p = c0 + lane * R0 + k;
        r[k] = (p < L_IN) ? xr[p] : 0.0f;
    }

    Chain<0>::run(r, A, cw4, cb4, lbuf, lane, wid);

    // FC(188 -> 91) + sigmoid.
    if (tid < FC_OUT) {
        float acc = fc_b[tid];
        const float4* wp = (const float4*)(fc_w + tid * FC_IN);  // 752B rows: 16B-aligned
        const float4* hp = (const float4*)lbuf;
#pragma unroll 4
        for (int q = 0; q < FC_IN / 4; ++q) {
            const float4 hv = hp[q];
            const float4 wv = wp[q];
            acc = fmaf(wv.x, hv.x, acc);
            acc = fmaf(wv.y, hv.y, acc);
            acc = fmaf(wv.z, hv.z, acc);
            acc = fmaf(wv.w, hv.w, acc);
        }
        out[(size_t)row * FC_OUT + tid] = 1.0f / (1.0f + expf(-acc));
    }
}

extern "C" void kernel_launch(void* const* d_in, const int* in_sizes, int n_in,
                              void* d_out, int out_size, void* d_ws, size_t ws_size,
                              hipStream_t stream) {
    const float* x      = (const float*)d_in[0];
    const float* conv_w = (const float*)d_in[1];
    const float* conv_b = (const float*)d_in[2];
    const float* fc_w   = (const float*)d_in[3];
    const float* fc_b   = (const float*)d_in[4];
    float* outp = (float*)d_out;

    const int batch = in_sizes[0] / L_IN;  // 1024 rows, 2 independent waves each
    conv_chain_kernel<<<batch, NT, 0, stream>>>(x, conv_w, conv_b, fc_w, fc_b, outp);
}